// Round 10
// baseline (189.924 us; speedup 1.0000x reference)
//
#include <hip/hip_runtime.h>
#include <hip/hip_bf16.h>
#include <math.h>

#define BB 2
#define CC 32
#define C8 4
#define NN 4096
#define JG 16         // j-split groups
#define JR (NN/JG)    // 256 keys per flash block
#define VSTRIDE 260   // LDS V row stride in shorts (520B == 8 mod 128 -> bank-rotated)
#define LOG2E 1.4426950408889634f

typedef __attribute__((ext_vector_type(8))) short short8;
typedef __attribute__((ext_vector_type(16))) float f32x16;

static __device__ __forceinline__ short f2bf(float x) {
    return __builtin_bit_cast(short, __float2bfloat16(x));
}
static __device__ __forceinline__ float bf2f(short s) {
    unsigned int u = ((unsigned int)(unsigned short)s) << 16;
    return __builtin_bit_cast(float, u);
}
// round-half-up bf16 pair pack: {bf16(b)|bf16(a)} (a low) -- plain C, compiler-scheduled
static __device__ __forceinline__ unsigned int pkbf(float a, float b) {
    unsigned int ua = __builtin_bit_cast(unsigned int, a) + 0x8000u;
    unsigned int ub = __builtin_bit_cast(unsigned int, b) + 0x8000u;
    return (ua >> 16) | (ub & 0xffff0000u);
}

// ---------------- K1: QKV projection (blocks 0..31) + CAM gram c<=d (blocks 32..295) ----
__global__ __launch_bounds__(256) void k1(const float* __restrict__ x,
    const float* __restrict__ wq, const float* __restrict__ bq,
    const float* __restrict__ wk, const float* __restrict__ bk,
    const float* __restrict__ wv, const float* __restrict__ bv,
    short* __restrict__ qpk, short* __restrict__ kpk, short* __restrict__ vbf,
    float* __restrict__ eng)
{
    if (blockIdx.x >= 32) {
        // ---- keng: one wave per unordered pair (c<=d); 528 pairs per batch ----
        int w = threadIdx.x >> 6, lane = threadIdx.x & 63;
        int pp = (blockIdx.x - 32)*4 + w;     // 0..1055
        int b = pp >= 528 ? 1 : 0;
        int t = pp - b*528;
        int c = 0, rem = t;
        while (rem >= CC - c) { rem -= CC - c; ++c; }
        int d = c + rem;
        const float4* xc = (const float4*)(x + ((size_t)b*CC + c)*NN);
        const float4* xd = (const float4*)(x + ((size_t)b*CC + d)*NN);
        float s = 0.f;
        for (int tt = lane; tt < NN/4; tt += 64) {
            float4 a = xc[tt], bb = xd[tt];
            s += a.x*bb.x + a.y*bb.y + a.z*bb.z + a.w*bb.w;
        }
        #pragma unroll
        for (int off = 32; off; off >>= 1) s += __shfl_down(s, off, 64);
        if (lane == 0) {
            eng[(b*CC + c)*CC + d] = s;
            eng[(b*CC + d)*CC + c] = s;
        }
        return;
    }
    // ---- kproj: thread = (b,n) ----
    __shared__ float swq[C8*CC], swk[C8*CC], swv[CC*CC], sbq[C8], sbk[C8], sbv[CC];
    int tid = threadIdx.x;
    for (int i = tid; i < C8*CC; i += 256) { swq[i] = wq[i]; swk[i] = wk[i]; }
    for (int i = tid; i < CC*CC; i += 256) swv[i] = wv[i];
    if (tid < C8) { sbq[tid] = bq[tid]; sbk[tid] = bk[tid]; }
    if (tid < CC) sbv[tid] = bv[tid];
    __syncthreads();
    int g = blockIdx.x*256 + tid;         // 0..8191
    int b = g >> 12; int n = g & (NN-1);
    const float* xb = x + (size_t)b*CC*NN + n;
    float xr[CC];
    #pragma unroll
    for (int c = 0; c < CC; ++c) xr[c] = xb[(size_t)c*NN];
    float qv[C8], kv[C8];
    #pragma unroll
    for (int o = 0; o < C8; ++o) { qv[o] = sbq[o]; kv[o] = sbk[o]; }
    #pragma unroll
    for (int c = 0; c < CC; ++c) {
        float xc = xr[c];
        #pragma unroll
        for (int o = 0; o < C8; ++o) { qv[o] += swq[o*CC+c]*xc; kv[o] += swk[o*CC+c]*xc; }
    }
    short4 qs = make_short4(f2bf(qv[0]*LOG2E), f2bf(qv[1]*LOG2E),
                            f2bf(qv[2]*LOG2E), f2bf(qv[3]*LOG2E));
    short4 ks = make_short4(f2bf(kv[0]), f2bf(kv[1]), f2bf(kv[2]), f2bf(kv[3]));
    *(short4*)(qpk + ((size_t)b*NN + n)*4) = qs;
    *(short4*)(kpk + ((size_t)b*NN + n)*4) = ks;
    #pragma unroll
    for (int o = 0; o < CC; ++o) {
        float av = sbv[o];
        #pragma unroll
        for (int c = 0; c < CC; ++c) av += swv[o*CC+c]*xr[c];
        vbf[((size_t)b*CC+o)*NN + n] = f2bf(av);
    }
}

// ---------------- K2: flash PAM + split-K last-block combine ----------------
// 1024 blocks = (b, it, jg). Flash: wave = 32 queries x 256 keys, dual 32x32 MFMA.
// After ticket, the 16th block per (b,it) combines all jg slices (L2-hot),
// inlines the CAM kwx fold, projects, and stores out. No separate kout launch.
__global__ __launch_bounds__(256, 3) void k2(const short* __restrict__ qpk,
    const short* __restrict__ kpk, const short* __restrict__ vbf,
    short* __restrict__ ppart, float* __restrict__ sep,
    const float* __restrict__ eng, const float* __restrict__ wo,
    const float* __restrict__ bo, const float* __restrict__ gp,
    const float* __restrict__ gc, const float* __restrict__ x,
    float* __restrict__ out, int* __restrict__ counters)
{
    __shared__ __align__(16) char smem[CC*VSTRIDE*2];   // 16640 B (V slab / finisher tables)
    __shared__ int is_last;

    int blk = blockIdx.x;            // 0..1023
    int b  = blk >> 9;
    int r  = blk & 511;
    int it = r >> 4;                 // 0..31 (128 queries)
    int jg = r & (JG-1);             // 0..15
    int jbase = jg*JR;
    int tid = threadIdx.x;

    // ---- stage V slab [32 rows][256 keys] -> LDS ----
    short* vsl = (short*)smem;
    {
        const short* vgp = vbf + (size_t)b*CC*NN + jbase;
        #pragma unroll
        for (int i2 = 0; i2 < 16; ++i2) {
            int idx = tid + i2*256;          // 0..4095 short4 granules
            int rr2 = idx >> 6;              // row 0..31 (64 granules/row)
            int cg  = idx & 63;
            *(short4*)(vsl + rr2*VSTRIDE + cg*4) =
                *(const short4*)(vgp + (size_t)rr2*NN + cg*4);
        }
    }

    int w = tid >> 6, lane = tid & 63;
    int qcol = lane & 31;
    int h = lane >> 5;
    int i0 = it*128 + w*32;

    // Q fragment (B-operand): col=q; contraction elems 0..3 (h==0 lanes) hold q*LOG2E
    short8 qf = {0,0,0,0,0,0,0,0};
    if (h == 0) {
        short4 qv = *(const short4*)(qpk + ((size_t)b*NN + i0 + qcol)*4);
        qf[0]=qv.x; qf[1]=qv.y; qf[2]=qv.z; qf[3]=qv.w;
    }
    // K slab hoisted to registers: 8 x short4 (h==0 lanes; zeros on h==1)
    short4 kreg[8];
    #pragma unroll
    for (int t = 0; t < 8; ++t) kreg[t] = make_short4(0,0,0,0);
    if (h == 0) {
        const short* kp0 = kpk + ((size_t)b*NN + jbase + qcol)*4;
        #pragma unroll
        for (int t = 0; t < 8; ++t) kreg[t] = *(const short4*)(kp0 + t*128);
    }
    const short* vrow = vsl + qcol*VSTRIDE;   // PV A-operand row c=lane&31

    f32x16 acc = {0,0,0,0,0,0,0,0,0,0,0,0,0,0,0,0};
    const f32x16 zz = {0,0,0,0,0,0,0,0,0,0,0,0,0,0,0,0};
    float se = 0.f;

    __syncthreads();   // V slab ready

    #pragma unroll
    for (int t = 0; t < 8; ++t) {
        short8 kf = {kreg[t].x, kreg[t].y, kreg[t].z, kreg[t].w, 0,0,0,0};
        f32x16 s = __builtin_amdgcn_mfma_f32_32x32x16_bf16(kf, qf, zz, 0, 0, 0);
        float p[16];
        #pragma unroll
        for (int i = 0; i < 16; ++i) p[i] = exp2f(s[i]);
        se += (((p[0]+p[1])+(p[2]+p[3])) + ((p[4]+p[5])+(p[6]+p[7])))
            + (((p[8]+p[9])+(p[10]+p[11])) + ((p[12]+p[13])+(p[14]+p[15])));
        unsigned int u0 = pkbf(p[0],p[1]),   u1 = pkbf(p[2],p[3]);
        unsigned int u2 = pkbf(p[4],p[5]),   u3 = pkbf(p[6],p[7]);
        unsigned int u4 = pkbf(p[8],p[9]),   u5 = pkbf(p[10],p[11]);
        unsigned int u6 = pkbf(p[12],p[13]), u7 = pkbf(p[14],p[15]);
        // V fragments from LDS at permuted key cols k(r,h) = (r&3)+8*(r>>2)+4h
        int vo = t*32 + 4*h;
        short4 a0 = *(const short4*)(vrow + vo);
        short4 a1 = *(const short4*)(vrow + vo + 8);
        short4 a2 = *(const short4*)(vrow + vo + 16);
        short4 a3 = *(const short4*)(vrow + vo + 24);
        short8 vf1 = {a0.x,a0.y,a0.z,a0.w, a1.x,a1.y,a1.z,a1.w};
        short8 pf1 = {(short)u0,(short)(u0>>16),(short)u1,(short)(u1>>16),
                      (short)u2,(short)(u2>>16),(short)u3,(short)(u3>>16)};
        acc = __builtin_amdgcn_mfma_f32_32x32x16_bf16(vf1, pf1, acc, 0, 0, 0);
        short8 vf2 = {a2.x,a2.y,a2.z,a2.w, a3.x,a3.y,a3.z,a3.w};
        short8 pf2 = {(short)u4,(short)(u4>>16),(short)u5,(short)(u5>>16),
                      (short)u6,(short)(u6>>16),(short)u7,(short)(u7>>16)};
        acc = __builtin_amdgcn_mfma_f32_32x32x16_bf16(vf2, pf2, acc, 0, 0, 0);
    }

    se += __shfl_xor(se, 32, 64);   // combine the two key-halves per q

    // ppart: [b][jg][it][w][lane][16] bf16 -> 2 coalesced 16B stores per lane
    {
        unsigned int pk[8];
        #pragma unroll
        for (int rr = 0; rr < 8; ++rr) pk[rr] = pkbf(acc[2*rr], acc[2*rr+1]);
        short* pb = ppart + (size_t)(b*JG + jg)*NN*CC
                  + ((size_t)(it*4 + w)*64 + lane)*16;
        *(uint4*)(pb)     = *(uint4*)(pk);
        *(uint4*)(pb + 8) = *(uint4*)(pk + 4);
        if (h == 0) sep[((size_t)(b*JG + jg))*NN + i0 + qcol] = se;
    }

    // ---- split-K ticket ----
    __threadfence();
    __syncthreads();
    if (tid == 0) {
        int old = atomicAdd(&counters[b*32 + it], 1);
        is_last = (old == JG-1);
    }
    __syncthreads();
    if (!is_last) return;
    __threadfence();

    // ================= finisher: combine + inline kwx + project =================
    float* se_ = (float*)smem;          // [1024]
    float* sc  = se_ + 1024;            // [1024]
    float* sw1 = sc  + 1024;            // [1024] gp*wo[o][c]
    float* swx = sw1 + 1024;            // [1024] folded CAM weight
    float* sbo = swx + 1024;            // [32]
    float gpv = gp[0], gcv = gc[0];
    for (int i = tid; i < CC*CC; i += 256) {
        se_[i] = eng[b*CC*CC + i];
        sw1[i] = gpv * wo[(i>>5)*64 + (i&31)];
    }
    if (tid < CC) sbo[tid] = bo[tid];
    __syncthreads();
    if (tid < CC) {
        float mn = se_[tid*CC];
        #pragma unroll
        for (int d = 1; d < CC; ++d) mn = fminf(mn, se_[tid*CC+d]);
        float pv[CC]; float s = 0.f;
        #pragma unroll
        for (int d = 0; d < CC; ++d) { pv[d] = __expf(mn - se_[tid*CC+d]); s += pv[d]; }
        float inv = 1.f/s;
        #pragma unroll
        for (int d = 0; d < CC; ++d) sc[tid*CC+d] = pv[d]*inv;
    }
    __syncthreads();
    for (int i = tid; i < CC*CC; i += 256) {
        int o = i >> 5, d = i & 31;
        float t2 = 0.f;
        #pragma unroll
        for (int c2 = 0; c2 < CC; ++c2) t2 += wo[o*64 + 32 + c2] * sc[c2*CC + d];
        swx[i] = wo[o*64 + d] + wo[o*64 + 32 + d] + gcv * t2;
    }
    __syncthreads();

    // thread = (token-local tl, o-half oh): tl = tid&127, oh = tid>>7
    int tl = tid & 127, oh = tid >> 7;
    int tn = it*128 + tl;
    int fw = tl >> 5, fq = tl & 31;
    size_t loff = ((size_t)(it*4 + fw)*64 + fq)*16;
    const short* pbase = ppart + (size_t)b*JG*NN*CC + loff;
    const float* sb = sep + (size_t)b*JG*NN + tn;

    float facc[CC]; float fse = 0.f;
    #pragma unroll
    for (int c = 0; c < CC; ++c) facc[c] = 0.f;
    #pragma unroll
    for (int j2 = 0; j2 < JG; ++j2) {
        const short* pr = pbase + (size_t)j2*NN*CC;
        short8 lo0 = *(const short8*)(pr);        // h=0, rr 0..7
        short8 hi0 = *(const short8*)(pr + 8);    // h=0, rr 8..15
        short8 lo1 = *(const short8*)(pr + 512);  // h=1 (lane+32), rr 0..7
        short8 hi1 = *(const short8*)(pr + 520);  // h=1, rr 8..15
        #pragma unroll
        for (int e = 0; e < 8; ++e) {
            int c0 = (e&3) + 8*(e>>2);
            facc[c0]    += bf2f(lo0[e]);
            facc[c0+4]  += bf2f(lo1[e]);
            facc[c0+16] += bf2f(hi0[e]);
            facc[c0+20] += bf2f(hi1[e]);
        }
        fse += sb[(size_t)j2*NN];
    }
    float inv = 1.f/fse;
    int ob0 = oh*16;
    float o_[16];
    #pragma unroll
    for (int o = 0; o < 16; ++o) o_[o] = sbo[ob0 + o];
    #pragma unroll
    for (int c = 0; c < CC; ++c) {
        float pc = facc[c]*inv;
        #pragma unroll
        for (int o = 0; o < 16; ++o) o_[o] += sw1[(ob0+o)*CC+c]*pc;
    }
    const float* xb = x + (size_t)b*CC*NN + tn;
    #pragma unroll
    for (int d = 0; d < CC; ++d) {
        float xd = xb[(size_t)d*NN];
        #pragma unroll
        for (int o = 0; o < 16; ++o) o_[o] += swx[(ob0+o)*CC+d]*xd;
    }
    float* ob = out + (size_t)b*CC*NN + tn;
    #pragma unroll
    for (int o = 0; o < 16; ++o) ob[(size_t)(ob0+o)*NN] = o_[o];
}

extern "C" void kernel_launch(void* const* d_in, const int* in_sizes, int n_in,
                              void* d_out, int out_size, void* d_ws, size_t ws_size,
                              hipStream_t stream)
{
    const float* x  = (const float*)d_in[0];
    const float* wq = (const float*)d_in[1];
    const float* bq = (const float*)d_in[2];
    const float* wk = (const float*)d_in[3];
    const float* bk = (const float*)d_in[4];
    const float* wv = (const float*)d_in[5];
    const float* bv = (const float*)d_in[6];
    const float* gp = (const float*)d_in[7];
    const float* gc = (const float*)d_in[8];
    const float* wo = (const float*)d_in[9];
    const float* bo = (const float*)d_in[10];

    char* wsb = (char*)d_ws;
    short* qpk     = (short*)(wsb + 0);          // 65536 B
    short* kpk     = (short*)(wsb + 65536);      // 65536 B
    short* vbf     = (short*)(wsb + 131072);     // 524288 B
    float* eng     = (float*)(wsb + 655360);     // 8192 B
    float* sep     = (float*)(wsb + 663552);     // 524288 B
    short* ppart   = (short*)(wsb + 1187840);    // 8388608 B
    int*   counters= (int*)  (wsb + 9576448);    // 256 B

    hipMemsetAsync(counters, 0, 64*sizeof(int), stream);
    k1<<<296, 256, 0, stream>>>(x, wq, bq, wk, bk, wv, bv, qpk, kpk, vbf, eng);
    k2<<<BB*32*JG, 256, 0, stream>>>(qpk, kpk, vbf, ppart, sep, eng, wo, bo,
                                     gp, gc, x, (float*)d_out, counters);
}

// Round 11
// 30.351 us; speedup vs baseline: 6.2575x; 6.2575x over previous
//
#include <hip/hip_runtime.h>
#include <hip/hip_bf16.h>
#include <math.h>

#define BB 2
#define CC 32
#define C8 4
#define NN 4096
#define VST 72        // LDS V tile row stride in shorts (144B: 16B-aligned, 4-way max conflict)
#define LOG2E 1.4426950408889634f

typedef __attribute__((ext_vector_type(8))) short short8;
typedef __attribute__((ext_vector_type(16))) float f32x16;

static __device__ __forceinline__ short f2bf(float x) {
    return __builtin_bit_cast(short, __float2bfloat16(x));
}
static __device__ __forceinline__ unsigned int pkbf(float a, float b) {
    unsigned int ua = __builtin_bit_cast(unsigned int, a) + 0x8000u;
    unsigned int ub = __builtin_bit_cast(unsigned int, b) + 0x8000u;
    return (ua >> 16) | (ub & 0xffff0000u);
}

// ---------------- K1: QKV projection (blocks 0..31) + CAM gram c<=d (blocks 32..295) ----
__global__ __launch_bounds__(256) void k1(const float* __restrict__ x,
    const float* __restrict__ wq, const float* __restrict__ bq,
    const float* __restrict__ wk, const float* __restrict__ bk,
    const float* __restrict__ wv, const float* __restrict__ bv,
    short* __restrict__ qpk, short* __restrict__ kpk, short* __restrict__ vbf,
    float* __restrict__ eng)
{
    if (blockIdx.x >= 32) {
        // ---- keng: one wave per unordered pair (c<=d); 528 pairs per batch ----
        int w = threadIdx.x >> 6, lane = threadIdx.x & 63;
        int pp = (blockIdx.x - 32)*4 + w;     // 0..1055
        int b = pp >= 528 ? 1 : 0;
        int t = pp - b*528;
        int c = 0, rem = t;
        while (rem >= CC - c) { rem -= CC - c; ++c; }
        int d = c + rem;
        const float4* xc = (const float4*)(x + ((size_t)b*CC + c)*NN);
        const float4* xd = (const float4*)(x + ((size_t)b*CC + d)*NN);
        float s = 0.f;
        for (int tt = lane; tt < NN/4; tt += 64) {
            float4 a = xc[tt], bb = xd[tt];
            s += a.x*bb.x + a.y*bb.y + a.z*bb.z + a.w*bb.w;
        }
        #pragma unroll
        for (int off = 32; off; off >>= 1) s += __shfl_down(s, off, 64);
        if (lane == 0) {
            eng[(b*CC + c)*CC + d] = s;
            eng[(b*CC + d)*CC + c] = s;
        }
        return;
    }
    // ---- kproj: thread = (b,n) ----
    __shared__ float swq[C8*CC], swk[C8*CC], swv[CC*CC], sbq[C8], sbk[C8], sbv[CC];
    int tid = threadIdx.x;
    for (int i = tid; i < C8*CC; i += 256) { swq[i] = wq[i]; swk[i] = wk[i]; }
    for (int i = tid; i < CC*CC; i += 256) swv[i] = wv[i];
    if (tid < C8) { sbq[tid] = bq[tid]; sbk[tid] = bk[tid]; }
    if (tid < CC) sbv[tid] = bv[tid];
    __syncthreads();
    int g = blockIdx.x*256 + tid;         // 0..8191
    int b = g >> 12; int n = g & (NN-1);
    const float* xb = x + (size_t)b*CC*NN + n;
    float xr[CC];
    #pragma unroll
    for (int c = 0; c < CC; ++c) xr[c] = xb[(size_t)c*NN];
    float qv[C8], kv[C8];
    #pragma unroll
    for (int o = 0; o < C8; ++o) { qv[o] = sbq[o]; kv[o] = sbk[o]; }
    #pragma unroll
    for (int c = 0; c < CC; ++c) {
        float xc = xr[c];
        #pragma unroll
        for (int o = 0; o < C8; ++o) { qv[o] += swq[o*CC+c]*xc; kv[o] += swk[o*CC+c]*xc; }
    }
    short4 qs = make_short4(f2bf(qv[0]*LOG2E), f2bf(qv[1]*LOG2E),
                            f2bf(qv[2]*LOG2E), f2bf(qv[3]*LOG2E));
    short4 ks = make_short4(f2bf(kv[0]), f2bf(kv[1]), f2bf(kv[2]), f2bf(kv[3]));
    *(short4*)(qpk + ((size_t)b*NN + n)*4) = qs;
    *(short4*)(kpk + ((size_t)b*NN + n)*4) = ks;
    #pragma unroll
    for (int o = 0; o < CC; ++o) {
        float av = sbv[o];
        #pragma unroll
        for (int c = 0; c < CC; ++c) av += swv[o*CC+c]*xr[c];
        vbf[((size_t)b*CC+o)*NN + n] = f2bf(av);
    }
}

// ---------------- K2: fused flash + in-block combine + CAM fold + projection ----
// 256 blocks = (b, 32-query tile), 512 threads = 8 waves. Wave w covers keys
// {p*512 + w*64 .. +64} over p=0..7 (512 keys). V staged per-wave in private
// double-buffered LDS tiles (no barriers in flash loop). Combine acc/sumexp
// across waves in LDS, per-block CAM wx fold, project, store out directly.
__global__ __launch_bounds__(512, 2) void k2(const short* __restrict__ qpk,
    const short* __restrict__ kpk, const short* __restrict__ vbf,
    const float* __restrict__ eng, const float* __restrict__ wo,
    const float* __restrict__ bo, const float* __restrict__ gp,
    const float* __restrict__ gc, const float* __restrict__ x,
    float* __restrict__ out)
{
    __shared__ __align__(16) char smem[73728];   // 8 waves x 2 bufs x 32 x VST shorts

    int blk = blockIdx.x;
    int b  = blk >> 7;
    int it = blk & 127;
    int i0 = it*32;
    int tid = threadIdx.x;
    int w = tid >> 6, lane = tid & 63;
    int qcol = lane & 31, h = lane >> 5;

    short* vb0 = (short*)smem + w*2*(32*VST);
    short* vb1 = vb0 + 32*VST;

    // V staging addresses: lane covers row rv, keys [ch*32, +32) of the wave's tile
    int rv = lane >> 1, ch = lane & 1;
    const short* vsrc = vbf + (size_t)b*CC*NN + (size_t)rv*NN + w*64 + ch*32;
    const short* ksrc = kpk + ((size_t)b*NN + w*64 + qcol)*4;

    // Q fragment (B-operand): contraction elems 0..3 on h==0 lanes hold q*LOG2E
    short8 qf = {0,0,0,0,0,0,0,0};
    if (h == 0) {
        short4 qv = *(const short4*)(qpk + ((size_t)b*NN + i0 + qcol)*4);
        qf[0]=qv.x; qf[1]=qv.y; qf[2]=qv.z; qf[3]=qv.w;
    }

    f32x16 acc = {0,0,0,0,0,0,0,0,0,0,0,0,0,0,0,0};
    const f32x16 zz = {0,0,0,0,0,0,0,0,0,0,0,0,0,0,0,0};
    float se = 0.f;

    // prologue: tile 0 loads (V: 4x16B per lane; K: 2x short4)
    short8 cv0 = *(const short8*)(vsrc);
    short8 cv1 = *(const short8*)(vsrc + 8);
    short8 cv2 = *(const short8*)(vsrc + 16);
    short8 cv3 = *(const short8*)(vsrc + 24);
    short4 ck0 = *(const short4*)(ksrc);
    short4 ck1 = *(const short4*)(ksrc + 128);

    #pragma unroll
    for (int t = 0; t < 8; ++t) {
        int tn = t < 7 ? t + 1 : 7;           // clamped prefetch
        short8 nv0 = *(const short8*)(vsrc + tn*512);
        short8 nv1 = *(const short8*)(vsrc + tn*512 + 8);
        short8 nv2 = *(const short8*)(vsrc + tn*512 + 16);
        short8 nv3 = *(const short8*)(vsrc + tn*512 + 24);
        short4 nk0 = *(const short4*)(ksrc + tn*2048);
        short4 nk1 = *(const short4*)(ksrc + tn*2048 + 128);

        short* wb = (t & 1) ? vb1 : vb0;
        short* wp = wb + rv*VST + ch*32;
        *(short8*)(wp)      = cv0;
        *(short8*)(wp + 8)  = cv1;
        *(short8*)(wp + 16) = cv2;
        *(short8*)(wp + 24) = cv3;

        const short* vrow = wb + qcol*VST;
        #pragma unroll
        for (int cI = 0; cI < 2; ++cI) {
            short4 kk = cI ? ck1 : ck0;
            short8 kf = {kk.x, kk.y, kk.z, kk.w, 0,0,0,0};
            f32x16 s = __builtin_amdgcn_mfma_f32_32x32x16_bf16(kf, qf, zz, 0, 0, 0);
            float p[16];
            #pragma unroll
            for (int i = 0; i < 16; ++i) p[i] = exp2f(s[i]);
            se += (((p[0]+p[1])+(p[2]+p[3])) + ((p[4]+p[5])+(p[6]+p[7])))
                + (((p[8]+p[9])+(p[10]+p[11])) + ((p[12]+p[13])+(p[14]+p[15])));
            unsigned int u0 = pkbf(p[0],p[1]),   u1 = pkbf(p[2],p[3]);
            unsigned int u2 = pkbf(p[4],p[5]),   u3 = pkbf(p[6],p[7]);
            unsigned int u4 = pkbf(p[8],p[9]),   u5 = pkbf(p[10],p[11]);
            unsigned int u6 = pkbf(p[12],p[13]), u7 = pkbf(p[14],p[15]);
            // V fragments at permuted key cols k(r,h) = (r&3)+8*(r>>2)+4h within chunk
            int vo = cI*32 + 4*h;
            short4 a0 = *(const short4*)(vrow + vo);
            short4 a1 = *(const short4*)(vrow + vo + 8);
            short4 a2 = *(const short4*)(vrow + vo + 16);
            short4 a3 = *(const short4*)(vrow + vo + 24);
            short8 vf1 = {a0.x,a0.y,a0.z,a0.w, a1.x,a1.y,a1.z,a1.w};
            short8 pf1 = {(short)u0,(short)(u0>>16),(short)u1,(short)(u1>>16),
                          (short)u2,(short)(u2>>16),(short)u3,(short)(u3>>16)};
            acc = __builtin_amdgcn_mfma_f32_32x32x16_bf16(vf1, pf1, acc, 0, 0, 0);
            short8 vf2 = {a2.x,a2.y,a2.z,a2.w, a3.x,a3.y,a3.z,a3.w};
            short8 pf2 = {(short)u4,(short)(u4>>16),(short)u5,(short)(u5>>16),
                          (short)u6,(short)(u6>>16),(short)u7,(short)(u7>>16)};
            acc = __builtin_amdgcn_mfma_f32_32x32x16_bf16(vf2, pf2, acc, 0, 0, 0);
        }
        cv0 = nv0; cv1 = nv1; cv2 = nv2; cv3 = nv3;
        ck0 = nk0; ck1 = nk1;
    }

    se += __shfl_xor(se, 32, 64);   // combine the two key-halves per q

    // ================= in-block combine + CAM fold + projection =================
    __syncthreads();                 // all waves done with their V buffers
    float* pamw = (float*)smem;      // [8][32*33]  per-wave acc tiles
    float* seL  = pamw + 8448;       // [8][32]
    float* sinv = seL  + 256;        // [32]
    float* pamn = sinv + 32;         // [32][33]  gp * pam_out / se
    float* xt   = pamn + 1056;       // [32][33]  x tile
    float* swo  = xt   + 1056;       // [32][33]  wo first half
    float* swx  = swo  + 1056;       // [32][33]  folded CAM weight
    float* sc   = swx  + 1056;       // [32][33]  cattn
    float* seng = sc   + 1056;       // [1024]
    float* sbo  = seng + 1024;       // [32]
    float* swo2 = sbo  + 32;         // [32][33]  wo second half

    #pragma unroll
    for (int r = 0; r < 16; ++r) {
        int c = (r&3) + 8*(r>>2) + 4*h;
        pamw[w*1056 + c*33 + qcol] = acc[r];
    }
    if (h == 0) seL[w*32 + qcol] = se;
    for (int i = tid; i < CC*CC; i += 512) {
        int o = i >> 5, c2 = i & 31;
        seng[i] = eng[b*CC*CC + i];
        swo [o*33 + c2] = wo[o*64 + c2];
        swo2[o*33 + c2] = wo[o*64 + 32 + c2];
        xt  [o*33 + c2] = x[(size_t)b*CC*NN + (size_t)o*NN + i0 + c2];
    }
    if (tid < CC) sbo[tid] = bo[tid];
    __syncthreads();

    if (tid < CC) {                  // 1/sumexp per query
        float s = 0.f;
        #pragma unroll
        for (int w2 = 0; w2 < 8; ++w2) s += seL[w2*32 + tid];
        sinv[tid] = 1.f / s;
    } else if (tid >= 64 && tid < 64 + CC) {   // CAM row softmax (separate wave)
        int r2 = tid - 64;
        float mn = seng[r2*32];
        #pragma unroll
        for (int d = 1; d < CC; ++d) mn = fminf(mn, seng[r2*32 + d]);
        float pv[CC]; float s = 0.f;
        #pragma unroll
        for (int d = 0; d < CC; ++d) { pv[d] = __expf(mn - seng[r2*32 + d]); s += pv[d]; }
        float inv = 1.f / s;
        #pragma unroll
        for (int d = 0; d < CC; ++d) sc[r2*33 + d] = pv[d]*inv;
    }
    __syncthreads();

    float gpv = gp[0], gcv = gc[0];
    for (int i = tid; i < CC*CC; i += 512) {
        int c = i >> 5, q = i & 31;
        float s2 = 0.f;
        #pragma unroll
        for (int w2 = 0; w2 < 8; ++w2) s2 += pamw[w2*1056 + c*33 + q];
        pamn[c*33 + q] = gpv * s2 * sinv[q];
        float t2 = 0.f;
        #pragma unroll
        for (int c2 = 0; c2 < CC; ++c2) t2 += swo2[c*33 + c2] * sc[c2*33 + q];
        swx[c*33 + q] = swo[c*33 + q] + swo2[c*33 + q] + gcv * t2;
    }
    __syncthreads();

    // projection: thread = (q, slot); outputs channels slot and slot+16
    int q = tid & 31, slot = tid >> 5;
    float o0 = sbo[slot], o1 = sbo[slot + 16];
    #pragma unroll
    for (int c = 0; c < CC; ++c) {
        float p  = pamn[c*33 + q];
        float xv = xt[c*33 + q];
        o0 += swo[slot*33 + c]      * p + swx[slot*33 + c]      * xv;
        o1 += swo[(slot+16)*33 + c] * p + swx[(slot+16)*33 + c] * xv;
    }
    float* ob = out + (size_t)b*CC*NN + i0 + q;
    ob[(size_t)slot*NN]      = o0;
    ob[(size_t)(slot+16)*NN] = o1;
}

extern "C" void kernel_launch(void* const* d_in, const int* in_sizes, int n_in,
                              void* d_out, int out_size, void* d_ws, size_t ws_size,
                              hipStream_t stream)
{
    const float* x  = (const float*)d_in[0];
    const float* wq = (const float*)d_in[1];
    const float* bq = (const float*)d_in[2];
    const float* wk = (const float*)d_in[3];
    const float* bk = (const float*)d_in[4];
    const float* wv = (const float*)d_in[5];
    const float* bv = (const float*)d_in[6];
    const float* gp = (const float*)d_in[7];
    const float* gc = (const float*)d_in[8];
    const float* wo = (const float*)d_in[9];
    const float* bo = (const float*)d_in[10];

    char* wsb = (char*)d_ws;
    short* qpk = (short*)(wsb + 0);          // 65536 B
    short* kpk = (short*)(wsb + 65536);      // 65536 B
    short* vbf = (short*)(wsb + 131072);     // 524288 B
    float* eng = (float*)(wsb + 655360);     // 8192 B

    k1<<<296, 256, 0, stream>>>(x, wq, bq, wk, bk, wv, bv, qpk, kpk, vbf, eng);
    k2<<<BB*128, 512, 0, stream>>>(qpk, kpk, vbf, eng, wo, bo, gp, gc, x, (float*)d_out);
}

// Round 12
// 28.411 us; speedup vs baseline: 6.6849x; 1.0683x over previous
//
#include <hip/hip_runtime.h>
#include <hip/hip_bf16.h>
#include <math.h>

#define BB 2
#define CC 32
#define C8 4
#define NN 4096
#define VST 72        // LDS V tile row stride in shorts (144B: 16B-aligned, 4-way max conflict)
#define LOG2E 1.4426950408889634f

typedef __attribute__((ext_vector_type(8))) short short8;
typedef __attribute__((ext_vector_type(16))) float f32x16;

static __device__ __forceinline__ short f2bf(float x) {
    return __builtin_bit_cast(short, __float2bfloat16(x));
}
static __device__ __forceinline__ unsigned int pkbf(float a, float b) {
    unsigned int ua = __builtin_bit_cast(unsigned int, a) + 0x8000u;
    unsigned int ub = __builtin_bit_cast(unsigned int, b) + 0x8000u;
    return (ua >> 16) | (ub & 0xffff0000u);
}

// ---------------- K1: QKV projection (blocks 0..63) + CAM gram c<=d (blocks 64..327) ----
__global__ __launch_bounds__(256) void k1(const float* __restrict__ x,
    const float* __restrict__ wq, const float* __restrict__ bq,
    const float* __restrict__ wk, const float* __restrict__ bk,
    const float* __restrict__ wv, const float* __restrict__ bv,
    short* __restrict__ qpk, short* __restrict__ kpk, short* __restrict__ vbf,
    float* __restrict__ eng)
{
    if (blockIdx.x >= 64) {
        // ---- keng: one wave per unordered pair (c<=d); 528 pairs per batch ----
        int w = threadIdx.x >> 6, lane = threadIdx.x & 63;
        int pp = (blockIdx.x - 64)*4 + w;     // 0..1055
        int b = pp >= 528 ? 1 : 0;
        int t = pp - b*528;
        int c = 0, rem = t;
        while (rem >= CC - c) { rem -= CC - c; ++c; }
        int d = c + rem;
        const float4* xc = (const float4*)(x + ((size_t)b*CC + c)*NN);
        const float4* xd = (const float4*)(x + ((size_t)b*CC + d)*NN);
        float s = 0.f;
        for (int tt = lane; tt < NN/4; tt += 64) {
            float4 a = xc[tt], bb = xd[tt];
            s += a.x*bb.x + a.y*bb.y + a.z*bb.z + a.w*bb.w;
        }
        #pragma unroll
        for (int off = 32; off; off >>= 1) s += __shfl_down(s, off, 64);
        if (lane == 0) {
            eng[(b*CC + c)*CC + d] = s;
            eng[(b*CC + d)*CC + c] = s;
        }
        return;
    }
    // ---- kproj: 64 blocks, thread = (token tl, half oh) ----
    __shared__ float swq[C8*CC], swk[C8*CC], swv[CC*CC], sbq[C8], sbk[C8], sbv[CC];
    int tid = threadIdx.x;
    for (int i = tid; i < C8*CC; i += 256) { swq[i] = wq[i]; swk[i] = wk[i]; }
    for (int i = tid; i < CC*CC; i += 256) swv[i] = wv[i];
    if (tid < C8) { sbq[tid] = bq[tid]; sbk[tid] = bk[tid]; }
    if (tid < CC) sbv[tid] = bv[tid];
    __syncthreads();
    int tl = tid & 127, oh = tid >> 7;
    int g = blockIdx.x*128 + tl;          // 0..8191
    int b = g >> 12; int n = g & (NN-1);
    const float* xb = x + (size_t)b*CC*NN + n;
    float xr[CC];
    #pragma unroll
    for (int c = 0; c < CC; ++c) xr[c] = xb[(size_t)c*NN];
    if (oh == 0) {
        float qv[C8], kv[C8];
        #pragma unroll
        for (int o = 0; o < C8; ++o) { qv[o] = sbq[o]; kv[o] = sbk[o]; }
        #pragma unroll
        for (int c = 0; c < CC; ++c) {
            float xc = xr[c];
            #pragma unroll
            for (int o = 0; o < C8; ++o) { qv[o] += swq[o*CC+c]*xc; kv[o] += swk[o*CC+c]*xc; }
        }
        short4 qs = make_short4(f2bf(qv[0]*LOG2E), f2bf(qv[1]*LOG2E),
                                f2bf(qv[2]*LOG2E), f2bf(qv[3]*LOG2E));
        short4 ks = make_short4(f2bf(kv[0]), f2bf(kv[1]), f2bf(kv[2]), f2bf(kv[3]));
        *(short4*)(qpk + ((size_t)b*NN + n)*4) = qs;
        *(short4*)(kpk + ((size_t)b*NN + n)*4) = ks;
    }
    int o0 = oh*16;
    #pragma unroll
    for (int o = 0; o < 16; ++o) {
        float av = sbv[o0+o];
        #pragma unroll
        for (int c = 0; c < CC; ++c) av += swv[(o0+o)*CC+c]*xr[c];
        vbf[((size_t)b*CC+o0+o)*NN + n] = f2bf(av);
    }
}

// ---------------- K2: fused flash + in-block combine + CAM fold + projection ----
// 256 blocks = (b, 32-query tile), 1024 threads = 16 waves (4/SIMD). Wave w
// covers keys {p*1024 + w*64 .. +64}, p=0..3 (256 keys). V staged per-wave in a
// private single-buffer LDS tile (DS ops are wave-FIFO -> no barrier needed).
// Combine acc/sumexp across 16 waves in LDS, CAM fold, project, store.
__global__ __launch_bounds__(1024, 4) void k2(const short* __restrict__ qpk,
    const short* __restrict__ kpk, const short* __restrict__ vbf,
    const float* __restrict__ eng, const float* __restrict__ wo,
    const float* __restrict__ bo, const float* __restrict__ gp,
    const float* __restrict__ gc, const float* __restrict__ x,
    float* __restrict__ out)
{
    __shared__ __align__(16) char smem[99328];   // flash: 16 waves x 32 x VST shorts (73728 B)

    int blk = blockIdx.x;
    int b  = blk >> 7;
    int it = blk & 127;
    int i0 = it*32;
    int tid = threadIdx.x;
    int w = tid >> 6, lane = tid & 63;
    int qcol = lane & 31, h = lane >> 5;

    short* vbuf = (short*)smem + w*(32*VST);

    // V staging: lane covers row rv, keys [ch*32, +32) of the wave's 64-key tile
    int rv = lane >> 1, ch = lane & 1;
    const short* vsrc = vbf + (size_t)b*CC*NN + (size_t)rv*NN + w*64 + ch*32;
    const short* ksrc = kpk + ((size_t)b*NN + w*64 + qcol)*4;

    // Q fragment (B-operand): contraction elems 0..3 on h==0 lanes hold q*LOG2E
    short8 qf = {0,0,0,0,0,0,0,0};
    if (h == 0) {
        short4 qv = *(const short4*)(qpk + ((size_t)b*NN + i0 + qcol)*4);
        qf[0]=qv.x; qf[1]=qv.y; qf[2]=qv.z; qf[3]=qv.w;
    }

    f32x16 acc = {0,0,0,0,0,0,0,0,0,0,0,0,0,0,0,0};
    const f32x16 zz = {0,0,0,0,0,0,0,0,0,0,0,0,0,0,0,0};
    float se = 0.f;

    // prologue: tile 0 loads (V: 4x16B per lane; K: 2x short4)
    short8 cv0 = *(const short8*)(vsrc);
    short8 cv1 = *(const short8*)(vsrc + 8);
    short8 cv2 = *(const short8*)(vsrc + 16);
    short8 cv3 = *(const short8*)(vsrc + 24);
    short4 ck0 = *(const short4*)(ksrc);
    short4 ck1 = *(const short4*)(ksrc + 128);

    #pragma unroll
    for (int t = 0; t < 4; ++t) {
        int tn = t < 3 ? t + 1 : 3;           // clamped prefetch (tile stride: 1024 keys)
        short8 nv0 = *(const short8*)(vsrc + tn*1024);
        short8 nv1 = *(const short8*)(vsrc + tn*1024 + 8);
        short8 nv2 = *(const short8*)(vsrc + tn*1024 + 16);
        short8 nv3 = *(const short8*)(vsrc + tn*1024 + 24);
        short4 nk0 = *(const short4*)(ksrc + tn*4096);
        short4 nk1 = *(const short4*)(ksrc + tn*4096 + 128);

        short* wp = vbuf + rv*VST + ch*32;    // single buffer: DS FIFO order makes
        *(short8*)(wp)      = cv0;            // this write safe after last tile's reads
        *(short8*)(wp + 8)  = cv1;
        *(short8*)(wp + 16) = cv2;
        *(short8*)(wp + 24) = cv3;

        const short* vrow = vbuf + qcol*VST;
        #pragma unroll
        for (int cI = 0; cI < 2; ++cI) {
            short4 kk = cI ? ck1 : ck0;
            short8 kf = {kk.x, kk.y, kk.z, kk.w, 0,0,0,0};
            f32x16 s = __builtin_amdgcn_mfma_f32_32x32x16_bf16(kf, qf, zz, 0, 0, 0);
            float p[16];
            #pragma unroll
            for (int i = 0; i < 16; ++i) p[i] = exp2f(s[i]);
            se += (((p[0]+p[1])+(p[2]+p[3])) + ((p[4]+p[5])+(p[6]+p[7])))
                + (((p[8]+p[9])+(p[10]+p[11])) + ((p[12]+p[13])+(p[14]+p[15])));
            unsigned int u0 = pkbf(p[0],p[1]),   u1 = pkbf(p[2],p[3]);
            unsigned int u2 = pkbf(p[4],p[5]),   u3 = pkbf(p[6],p[7]);
            unsigned int u4 = pkbf(p[8],p[9]),   u5 = pkbf(p[10],p[11]);
            unsigned int u6 = pkbf(p[12],p[13]), u7 = pkbf(p[14],p[15]);
            // V fragments at permuted key cols k(r,h) = (r&3)+8*(r>>2)+4h within chunk
            int vo = cI*32 + 4*h;
            short4 a0 = *(const short4*)(vrow + vo);
            short4 a1 = *(const short4*)(vrow + vo + 8);
            short4 a2 = *(const short4*)(vrow + vo + 16);
            short4 a3 = *(const short4*)(vrow + vo + 24);
            short8 vf1 = {a0.x,a0.y,a0.z,a0.w, a1.x,a1.y,a1.z,a1.w};
            short8 pf1 = {(short)u0,(short)(u0>>16),(short)u1,(short)(u1>>16),
                          (short)u2,(short)(u2>>16),(short)u3,(short)(u3>>16)};
            acc = __builtin_amdgcn_mfma_f32_32x32x16_bf16(vf1, pf1, acc, 0, 0, 0);
            short8 vf2 = {a2.x,a2.y,a2.z,a2.w, a3.x,a3.y,a3.z,a3.w};
            short8 pf2 = {(short)u4,(short)(u4>>16),(short)u5,(short)(u5>>16),
                          (short)u6,(short)(u6>>16),(short)u7,(short)(u7>>16)};
            acc = __builtin_amdgcn_mfma_f32_32x32x16_bf16(vf2, pf2, acc, 0, 0, 0);
        }
        cv0 = nv0; cv1 = nv1; cv2 = nv2; cv3 = nv3;
        ck0 = nk0; ck1 = nk1;
    }

    se += __shfl_xor(se, 32, 64);   // combine the two key-halves per q

    // ================= in-block combine + CAM fold + projection =================
    __syncthreads();                 // all waves done with their V buffers
    float* pamw = (float*)smem;      // [16][32*33]  per-wave acc tiles
    float* seL  = pamw + 16*1056;    // [16][32]
    float* sinv = seL  + 512;        // [32]
    float* pamn = sinv + 32;         // [32][33]  gp * pam_out / se
    float* xt   = pamn + 1056;       // [32][33]  x tile
    float* swo  = xt   + 1056;       // [32][33]  wo first half
    float* swx  = swo  + 1056;       // [32][33]  folded CAM weight
    float* sc   = swx  + 1056;       // [32][33]  cattn
    float* seng = sc   + 1056;       // [1024]
    float* sbo  = seng + 1024;       // [32]
    float* swo2 = sbo  + 32;         // [32][33]  wo second half

    #pragma unroll
    for (int r = 0; r < 16; ++r) {
        int c = (r&3) + 8*(r>>2) + 4*h;
        pamw[w*1056 + c*33 + qcol] = acc[r];
    }
    if (h == 0) seL[w*32 + qcol] = se;
    for (int i = tid; i < CC*CC; i += 1024) {
        int o = i >> 5, c2 = i & 31;
        seng[i] = eng[b*CC*CC + i];
        swo [o*33 + c2] = wo[o*64 + c2];
        swo2[o*33 + c2] = wo[o*64 + 32 + c2];
        xt  [o*33 + c2] = x[(size_t)b*CC*NN + (size_t)o*NN + i0 + c2];
    }
    if (tid < CC) sbo[tid] = bo[tid];
    __syncthreads();

    if (tid < CC) {                  // 1/sumexp per query
        float s = 0.f;
        #pragma unroll
        for (int w2 = 0; w2 < 16; ++w2) s += seL[w2*32 + tid];
        sinv[tid] = 1.f / s;
    } else if (tid >= 64 && tid < 64 + CC) {   // CAM row softmax (separate wave)
        int r2 = tid - 64;
        float mn = seng[r2*32];
        #pragma unroll
        for (int d = 1; d < CC; ++d) mn = fminf(mn, seng[r2*32 + d]);
        float pv[CC]; float s = 0.f;
        #pragma unroll
        for (int d = 0; d < CC; ++d) { pv[d] = __expf(mn - seng[r2*32 + d]); s += pv[d]; }
        float inv = 1.f / s;
        #pragma unroll
        for (int d = 0; d < CC; ++d) sc[r2*33 + d] = pv[d]*inv;
    }
    __syncthreads();

    float gpv = gp[0], gcv = gc[0];
    for (int i = tid; i < CC*CC; i += 1024) {
        int c = i >> 5, q = i & 31;
        float s2 = 0.f;
        #pragma unroll
        for (int w2 = 0; w2 < 16; ++w2) s2 += pamw[w2*1056 + c*33 + q];
        pamn[c*33 + q] = gpv * s2 * sinv[q];
        float t2 = 0.f;
        #pragma unroll
        for (int c2 = 0; c2 < CC; ++c2) t2 += swo2[c*33 + c2] * sc[c2*33 + q];
        swx[c*33 + q] = swo[c*33 + q] + swo2[c*33 + q] + gcv * t2;
    }
    __syncthreads();

    // projection: thread = (q, slot) -> one output channel per thread
    int q = tid & 31, slot = (tid >> 5) & 31;
    float o0 = sbo[slot];
    #pragma unroll
    for (int c = 0; c < CC; ++c) {
        o0 += swo[slot*33 + c] * pamn[c*33 + q] + swx[slot*33 + c] * xt[c*33 + q];
    }
    out[(size_t)b*CC*NN + (size_t)slot*NN + i0 + q] = o0;
}

extern "C" void kernel_launch(void* const* d_in, const int* in_sizes, int n_in,
                              void* d_out, int out_size, void* d_ws, size_t ws_size,
                              hipStream_t stream)
{
    const float* x  = (const float*)d_in[0];
    const float* wq = (const float*)d_in[1];
    const float* bq = (const float*)d_in[2];
    const float* wk = (const float*)d_in[3];
    const float* bk = (const float*)d_in[4];
    const float* wv = (const float*)d_in[5];
    const float* bv = (const float*)d_in[6];
    const float* gp = (const float*)d_in[7];
    const float* gc = (const float*)d_in[8];
    const float* wo = (const float*)d_in[9];
    const float* bo = (const float*)d_in[10];

    char* wsb = (char*)d_ws;
    short* qpk = (short*)(wsb + 0);          // 65536 B
    short* kpk = (short*)(wsb + 65536);      // 65536 B
    short* vbf = (short*)(wsb + 131072);     // 524288 B
    float* eng = (float*)(wsb + 655360);     // 8192 B

    k1<<<328, 256, 0, stream>>>(x, wq, bq, wk, bk, wv, bv, qpk, kpk, vbf, eng);
    k2<<<BB*128, 1024, 0, stream>>>(qpk, kpk, vbf, eng, wo, bo, gp, gc, x, (float*)d_out);
}